// Round 9
// baseline (207.896 us; speedup 1.0000x reference)
//
#include <hip/hip_runtime.h>
#include <stdint.h>

#define B_SZ  4096
#define HEADS 16
#define HD    64
#define M_SZ  4096
#define K_IN  1024
#define SW    72    // padded LDS row stride (f16 elems)
#define LOG2E 1.44269504088896f

typedef _Float16 f16;
typedef f16  f16x2 __attribute__((ext_vector_type(2)));
typedef f16  f16x4 __attribute__((ext_vector_type(4)));
typedef f16  f16x8 __attribute__((ext_vector_type(8)));
typedef float f32x4 __attribute__((ext_vector_type(4)));

union U8 { uint4 u4; f16x8 h8; unsigned int ui[4]; unsigned short us[8]; };

__device__ __forceinline__ unsigned short f2h(float f) {
    _Float16 h = (_Float16)f;
    return __builtin_bit_cast(unsigned short, h);
}
__device__ __forceinline__ f16x8 ldsv8(const unsigned short* p) {
    U8 u; u.u4 = *reinterpret_cast<const uint4*>(p); return u.h8;
}

#if __has_builtin(__builtin_amdgcn_exp2f)
#define EXP2F(x) __builtin_amdgcn_exp2f(x)
#else
#define EXP2F(x) __expf((x) * 0.6931471805599453f)
#endif

#if __has_builtin(__builtin_amdgcn_cvt_pkrtz)
#define PK2(a, b) __builtin_bit_cast(unsigned int, __builtin_amdgcn_cvt_pkrtz((a), (b)))
#else
__device__ __forceinline__ unsigned int PK2(float a, float b) {
    return (unsigned int)f2h(a) | ((unsigned int)f2h(b) << 16);
}
#endif

// async global -> LDS: lane i's 16 B land at ldsbase + i*16
__device__ __forceinline__ void gload_lds16(const void* g, void* l) {
    __builtin_amdgcn_global_load_lds(
        (const __attribute__((address_space(1))) void*)g,
        (__attribute__((address_space(3))) void*)l, 16, 0, 0);
}

// ---------------------------------------------------------------------------
// Kernel F: FUSED prep_mem + qproj (independent block ranges, one dispatch).
//   blocks 0..1023   : normalize memories -> fragment-ordered F  [r0 verbatim,
//                      grid flattened: tl = b & 63, h = b >> 6]
//   blocks 1024..1535: q = x @ Wq^T reading f32 DIRECTLY (k_conv absorbed:
//                      staging converts via cvt_pkrtz), SW=72 padded LDS
//                      (conflict-free frag reads), fused L2 norm epilogue.
// Cuts kernel dispatches 4 -> 2 and deletes the 30 MB xh/Wh round-trip.
// ---------------------------------------------------------------------------
__global__ __launch_bounds__(256, 2) void k_fused(const float* __restrict__ x,
                                                  const float* __restrict__ Wq,
                                                  const float* __restrict__ mem,
                                                  unsigned short* __restrict__ F,
                                                  unsigned short* __restrict__ qn) {
    __shared__ __align__(16) unsigned char smem[27648];   // max(prep 10.5K, qproj 27K)
    const int b = blockIdx.x;
    const int t = threadIdx.x;

    if (b < 1024) {
        // ================= prep_mem part (verbatim body) =================
        float* part  = reinterpret_cast<float*>(smem);            // [64][4]
        float* scale = part + 256;                                // [64]
        unsigned short* Tn = reinterpret_cast<unsigned short*>(scale + 64);  // 64*SW

        const int h  = b >> 6;
        const int tl = b & 63;
        const int m0 = tl * 64;
        const int r = t >> 2;
        const int c = t & 3;

        const float* src = mem + ((size_t)(h * M_SZ + m0 + r)) * HD + c * 16;
        float v[16];
        float ss = 0.f;
#pragma unroll
        for (int i = 0; i < 4; i++) {
            float4 f = reinterpret_cast<const float4*>(src)[i];
            v[4*i+0] = f.x; v[4*i+1] = f.y; v[4*i+2] = f.z; v[4*i+3] = f.w;
            ss += f.x*f.x + f.y*f.y + f.z*f.z + f.w*f.w;
        }
        part[r * 4 + c] = ss;
        __syncthreads();
        if (t < 64) {
            float s = part[t*4+0] + part[t*4+1] + part[t*4+2] + part[t*4+3];
            scale[t] = rsqrtf(s);
        }
        __syncthreads();
        const float sc = scale[r];

        U8 a2, b2;
#pragma unroll
        for (int i = 0; i < 8; i++) { a2.us[i] = f2h(v[i] * sc); b2.us[i] = f2h(v[8 + i] * sc); }
        *reinterpret_cast<uint4*>(&Tn[r * SW + c * 16])     = a2.u4;
        *reinterpret_cast<uint4*>(&Tn[r * SW + c * 16 + 8]) = b2.u4;
        __syncthreads();

        const int w = t >> 6, lane = t & 63;
        const int l15 = lane & 15, quad = lane >> 4;
        unsigned short* Fd = F + ((size_t)(h * 64 + tl) * 16) * 512;

        // QK A-frag chunks (permuted m)
#pragma unroll
        for (int i = 0; i < 2; i++) {
            const int ch = w * 2 + i, g = ch >> 1, s = ch & 1;
            const int mp = 32 * (g >> 1) + ((l15 >> 2) * 8) + 4 * (g & 1) + (l15 & 3);
            uint4 vv = *reinterpret_cast<const uint4*>(&Tn[mp * SW + s * 32 + quad * 8]);
            *reinterpret_cast<uint4*>(Fd + ch * 512 + lane * 8) = vv;
        }
        // PV B-frag chunks (physical m)
#pragma unroll
        for (int i = 0; i < 2; i++) {
            const int c2 = w * 2 + i, p = c2 >> 2, n = c2 & 3;
            U8 u;
#pragma unroll
            for (int j = 0; j < 8; j++)
                u.us[j] = Tn[(32 * p + quad * 8 + j) * SW + n * 16 + l15];
            *reinterpret_cast<uint4*>(Fd + (8 + c2) * 512 + lane * 8) = u.u4;
        }
        return;
    }

    // ================= qproj part (f32 sources, SW=72 LDS) =================
    unsigned short* As = reinterpret_cast<unsigned short*>(smem);   // [128][SW]
    unsigned short* Bs = As + 128 * SW;                             // [64][SW]

    const int bq = b - 1024;
    const int b0 = (bq & 31) * 128;
    const int n0 = (bq >> 5) * 64;      // == h*64
    const int w = t >> 6, lane = t & 63;
    const int l15 = lane & 15, quad = lane >> 4;

    f32x4 acc[2][4] = {};

    for (int kb = 0; kb < K_IN; kb += 64) {
        __syncthreads();
        {
            const float* px = x  + (size_t)(b0 + (t >> 1)) * K_IN + kb + (t & 1) * 32;
            const float* pw = Wq + (size_t)(n0 + (t >> 2)) * K_IN + kb + (t & 3) * 16;
            float4 av[8];
#pragma unroll
            for (int i = 0; i < 8; i++) av[i] = reinterpret_cast<const float4*>(px)[i];
            float4 bv[4];
#pragma unroll
            for (int i = 0; i < 4; i++) bv[i] = reinterpret_cast<const float4*>(pw)[i];
#pragma unroll
            for (int i = 0; i < 4; i++) {
                U8 u;
                u.ui[0] = PK2(av[2*i].x,   av[2*i].y);
                u.ui[1] = PK2(av[2*i].z,   av[2*i].w);
                u.ui[2] = PK2(av[2*i+1].x, av[2*i+1].y);
                u.ui[3] = PK2(av[2*i+1].z, av[2*i+1].w);
                *reinterpret_cast<uint4*>(&As[(t >> 1) * SW + (t & 1) * 32 + i * 8]) = u.u4;
            }
#pragma unroll
            for (int i = 0; i < 2; i++) {
                U8 u;
                u.ui[0] = PK2(bv[2*i].x,   bv[2*i].y);
                u.ui[1] = PK2(bv[2*i].z,   bv[2*i].w);
                u.ui[2] = PK2(bv[2*i+1].x, bv[2*i+1].y);
                u.ui[3] = PK2(bv[2*i+1].z, bv[2*i+1].w);
                *reinterpret_cast<uint4*>(&Bs[(t >> 2) * SW + (t & 3) * 16 + i * 8]) = u.u4;
            }
        }
        __syncthreads();

#pragma unroll
        for (int s = 0; s < 2; s++) {
            f16x8 af[2];
#pragma unroll
            for (int qg = 0; qg < 2; qg++)
                af[qg] = ldsv8(&As[(w * 32 + qg * 16 + l15) * SW + s * 32 + quad * 8]);
#pragma unroll
            for (int g = 0; g < 4; g++) {
                f16x8 bf_ = ldsv8(&Bs[(g * 16 + l15) * SW + s * 32 + quad * 8]);
#pragma unroll
                for (int qg = 0; qg < 2; qg++)
                    acc[qg][g] = __builtin_amdgcn_mfma_f32_16x16x32_f16(af[qg], bf_, acc[qg][g], 0, 0, 0);
            }
        }
    }

    __syncthreads();
    unsigned short* Ct = As;   // 128 x SW scratch
#pragma unroll
    for (int qg = 0; qg < 2; qg++) {
        float ssq[4];
#pragma unroll
        for (int r = 0; r < 4; r++) {
            float s = 0.f;
#pragma unroll
            for (int g = 0; g < 4; g++) s += acc[qg][g][r] * acc[qg][g][r];
            ssq[r] = s;
        }
#pragma unroll
        for (int mask = 1; mask <= 8; mask <<= 1)
#pragma unroll
            for (int r = 0; r < 4; r++) ssq[r] += __shfl_xor(ssq[r], mask, 64);
#pragma unroll
        for (int r = 0; r < 4; r++) {
            float inv = rsqrtf(ssq[r]) * LOG2E;
#pragma unroll
            for (int g = 0; g < 4; g++)
                Ct[(w * 32 + qg * 16 + quad * 4 + r) * SW + g * 16 + l15] = f2h(acc[qg][g][r] * inv);
        }
    }
    __syncthreads();

    const int row = t >> 1, half = (t & 1) * 32;
    unsigned short* dq = qn + (size_t)(b0 + row) * 1024 + n0 + half;
#pragma unroll
    for (int i = 0; i < 4; i++)
        reinterpret_cast<uint4*>(dq)[i] = *reinterpret_cast<const uint4*>(&Ct[row * SW + half + i * 8]);
}

// ---------------------------------------------------------------------------
// Kernel 3: fused attention v7 — FROZEN at round-7 state (77.4 µs; at the
// family floor under the per-SIMD MFMA+VALU serialize model).
// ---------------------------------------------------------------------------
__global__ __launch_bounds__(256, 2) void k_attn(const unsigned short* __restrict__ qn,
                                                 const unsigned short* __restrict__ F,
                                                 float* __restrict__ out) {
    __shared__ unsigned short buf[4][8192];   // 4 x 16 KB

    const int b = blockIdx.x;
    const int h  = 2 * (b & 7) + (b >> 8);    // XCD k serves heads {2k, 2k+1}
    const int b0 = ((b >> 3) & 31) * 128;
    const int t = threadIdx.x;
    const int w = t >> 6, lane = t & 63;
    const int l15 = lane & 15, quad = lane >> 4;

    const f32x4 Z = {0.f, 0.f, 0.f, 0.f};

    // Q as B-operand of 16x16x32: lane holds Q[q=l15][d = s*32 + quad*8 + j]
    f16x8 qf[2][2];
#pragma unroll
    for (int qg = 0; qg < 2; qg++)
#pragma unroll
        for (int s = 0; s < 2; s++) {
            U8 u;
            u.u4 = *reinterpret_cast<const uint4*>(
                qn + (size_t)(b0 + w * 32 + qg * 16 + l15) * 1024 + h * 64 + s * 32 + quad * 8);
            qf[qg][s] = u.h8;
        }

    const unsigned short* Fh = F + (size_t)h * 64 * 8192;

    f32x4 accO[2][4] = {};
    float lsum[2] = {0.f, 0.f};

    // pipeline register state (double-buffered)
    f16x8 puA[2][2], puB[2][2];   // P A-frags [qg][p]
    f16x8 bwA[8],   bwB[8];       // V B-frags [p*4+n]

#if __has_builtin(__builtin_amdgcn_fdot2)
    const f16x2 one2 = {(_Float16)1.f, (_Float16)1.f};
#define LSUM4(qgi, puv)                                                          \
    {                                                                            \
        float s_ = lsum[qgi];                                                    \
        s_ = __builtin_amdgcn_fdot2(__builtin_bit_cast(f16x2, (puv).ui[0]), one2, s_, false); \
        s_ = __builtin_amdgcn_fdot2(__builtin_bit_cast(f16x2, (puv).ui[1]), one2, s_, false); \
        s_ = __builtin_amdgcn_fdot2(__builtin_bit_cast(f16x2, (puv).ui[2]), one2, s_, false); \
        s_ = __builtin_amdgcn_fdot2(__builtin_bit_cast(f16x2, (puv).ui[3]), one2, s_, false); \
        lsum[qgi] = s_;                                                          \
    }
#else
#define LSUM4(qgi, puv)                                                          \
    {                                                                            \
        float a0 = (float)(puv).h8[0] + (float)(puv).h8[1];                      \
        float a1 = (float)(puv).h8[2] + (float)(puv).h8[3];                      \
        float a2 = (float)(puv).h8[4] + (float)(puv).h8[5];                      \
        float a3 = (float)(puv).h8[6] + (float)(puv).h8[7];                      \
        lsum[qgi] += (a0 + a1) + (a2 + a3);                                      \
    }
#endif

    // ---- prologue: stage tiles 0..2, compute pu(0)/bw(0) into set A ----
#pragma unroll
    for (int tp = 0; tp < 3; tp++)
#pragma unroll
        for (int i = 0; i < 4; i++) {
            const int ch = w * 4 + i;
            gload_lds16(Fh + (size_t)tp * 8192 + ch * 512 + lane * 8, &buf[tp][ch * 512]);
        }
    __syncthreads();
    {
        f16x8 am[8];
#pragma unroll
        for (int ch = 0; ch < 8; ch++) am[ch] = ldsv8(&buf[0][ch * 512 + lane * 8]);
#pragma unroll
        for (int ch = 0; ch < 8; ch++) bwA[ch] = ldsv8(&buf[0][(8 + ch) * 512 + lane * 8]);
#pragma unroll
        for (int g = 0; g < 4; g++) {
            const int qg = g >> 1, p = g & 1;
            f32x4 t0 = __builtin_amdgcn_mfma_f32_16x16x32_f16(am[4*p+0], qf[qg][0], Z, 0, 0, 0);
            t0 = __builtin_amdgcn_mfma_f32_16x16x32_f16(am[4*p+1], qf[qg][1], t0, 0, 0, 0);
            f32x4 t1 = __builtin_amdgcn_mfma_f32_16x16x32_f16(am[4*p+2], qf[qg][0], Z, 0, 0, 0);
            t1 = __builtin_amdgcn_mfma_f32_16x16x32_f16(am[4*p+3], qf[qg][1], t1, 0, 0, 0);
            float p0 = EXP2F(t0[0]), p1 = EXP2F(t0[1]), p2 = EXP2F(t0[2]), p3 = EXP2F(t0[3]);
            float p4 = EXP2F(t1[0]), p5 = EXP2F(t1[1]), p6 = EXP2F(t1[2]), p7 = EXP2F(t1[3]);
            U8 pu;
            pu.ui[0] = PK2(p0, p1);
            pu.ui[1] = PK2(p2, p3);
            pu.ui[2] = PK2(p4, p5);
            pu.ui[3] = PK2(p6, p7);
            LSUM4(qg, pu);
            puA[qg][p] = pu.h8;
        }
    }

    // ---- pipelined body: PV(tl) || QK(tl+1); barrier hoisted to window ----
    auto body = [&](int tl, f16x8 (&puC)[2][2], f16x8 (&bwC)[8],
                            f16x8 (&puN)[2][2], f16x8 (&bwN)[8]) {
        const unsigned short* lb = buf[(tl + 1) & 3];
        f16x8 amn[8];
#pragma unroll
        for (int ch = 0; ch < 8; ch++) amn[ch] = ldsv8(&lb[ch * 512 + lane * 8]);
#pragma unroll
        for (int ch = 0; ch < 8; ch++) bwN[ch] = ldsv8(&lb[(8 + ch) * 512 + lane * 8]);
        if (tl + 3 < 64) {   // stage tile tl+3 into buf[(tl+3)&3]
            const unsigned short* gsrc = Fh + (size_t)(tl + 3) * 8192;
#pragma unroll
            for (int i = 0; i < 4; i++) {
                const int ch = w * 4 + i;
                gload_lds16(gsrc + ch * 512 + lane * 8, &buf[(tl + 3) & 3][ch * 512]);
            }
        }

        f32x4 sa[4], sb[4];
        auto expPack = [&](int g) {
            const int qg = g >> 1, p = g & 1;
            float p0 = EXP2F(sa[g][0]), p1 = EXP2F(sa[g][1]), p2 = EXP2F(sa[g][2]), p3 = EXP2F(sa[g][3]);
            float p4 = EXP2F(sb[g][0]), p5 = EXP2F(sb[g][1]), p6 = EXP2F(sb[g][2]), p7 = EXP2F(sb[g][3]);
            U8 pu;
            pu.ui[0] = PK2(p0, p1);
            pu.ui[1] = PK2(p2, p3);
            pu.ui[2] = PK2(p4, p5);
            pu.ui[3] = PK2(p6, p7);
            LSUM4(qg, pu);
            puN[qg][p] = pu.h8;
        };

#pragma unroll
        for (int g = 0; g < 4; g++) {
            const int qg = g >> 1, p = g & 1;
            __builtin_amdgcn_s_setprio(1);
            // QK group g of tile tl+1
            f32x4 t0 = __builtin_amdgcn_mfma_f32_16x16x32_f16(amn[4*p+0], qf[qg][0], Z, 0, 0, 0);
            t0 = __builtin_amdgcn_mfma_f32_16x16x32_f16(amn[4*p+1], qf[qg][1], t0, 0, 0, 0);
            f32x4 t1 = __builtin_amdgcn_mfma_f32_16x16x32_f16(amn[4*p+2], qf[qg][0], Z, 0, 0, 0);
            t1 = __builtin_amdgcn_mfma_f32_16x16x32_f16(amn[4*p+3], qf[qg][1], t1, 0, 0, 0);
            sa[g] = t0; sb[g] = t1;
            // PV group g of tile tl (independent of the QK above)
#pragma unroll
            for (int n = 0; n < 4; n++)
                accO[qg][n] = __builtin_amdgcn_mfma_f32_16x16x32_f16(puC[qg][p], bwC[p * 4 + n], accO[qg][n], 0, 0, 0);
            __builtin_amdgcn_s_setprio(0);
            // exp of the PREVIOUS group (its QK results are long since ready)
            if (g >= 1) expPack(g - 1);
        }
        expPack(3);
    };

    // windows of 2 tiles: barrier at even tl (0,2,...,62) -> 32 in-loop syncs
    for (int tt = 0; tt < 31; ++tt) {
        __syncthreads();
        body(2 * tt,     puA, bwA, puB, bwB);
        body(2 * tt + 1, puB, bwB, puA, bwA);
    }
    __syncthreads();
    body(62, puA, bwA, puB, bwB);

    // ---- epilogue: PV(63) from register set B, then normalize + store ----
#pragma unroll
    for (int g = 0; g < 4; g++) {
        const int qg = g >> 1, p = g & 1;
#pragma unroll
        for (int n = 0; n < 4; n++)
            accO[qg][n] = __builtin_amdgcn_mfma_f32_16x16x32_f16(puB[qg][p], bwB[p * 4 + n], accO[qg][n], 0, 0, 0);
    }

#pragma unroll
    for (int qg = 0; qg < 2; qg++) {
        float s = lsum[qg];
        s += __shfl_xor(s, 16, 64);
        s += __shfl_xor(s, 32, 64);
        float inv = 8.0f / s;    // sqrt(HEAD_DIM) = 8
#pragma unroll
        for (int r = 0; r < 4; r++) {
            float iv = __shfl(inv, quad * 4 + r, 64);
            float* po = out + (size_t)(b0 + w * 32 + qg * 16 + quad * 4 + r) * 1024 + h * 64;
#pragma unroll
            for (int n = 0; n < 4; n++)
                po[n * 16 + l15] = accO[qg][n][r] * iv;
        }
    }
}

// ---------------------------------------------------------------------------
extern "C" void kernel_launch(void* const* d_in, const int* in_sizes, int n_in,
                              void* d_out, int out_size, void* d_ws, size_t ws_size,
                              hipStream_t stream) {
    (void)in_sizes; (void)n_in; (void)out_size; (void)ws_size;
    const float* x   = (const float*)d_in[0];
    const float* Wq  = (const float*)d_in[1];
    const float* mem = (const float*)d_in[2];
    float* out = (float*)d_out;

    unsigned short* qn = (unsigned short*)d_ws;                 // 8 MB
    unsigned short* F  = qn + (size_t)B_SZ * 1024;              // 16 MB (frag-ordered)

    k_fused<<<1536, 256, 0, stream>>>(x, Wq, mem, F, qn);
    k_attn <<<512,  256, 0, stream>>>(qn, F, out);
}